// Round 5
// baseline (6329.831 us; speedup 1.0000x reference)
//
#include <hip/hip_runtime.h>

#define C_DIM 128
#define NPOS 65536
#define NSTEPS 12
#define TILE_P 32
#define FBLOCKS 256
#define FTHREADS 512
#define TOTAL_WAVES 2048
#define TILES_PER_WAVE 2

typedef short short8 __attribute__((ext_vector_type(8)));
typedef float floatx4 __attribute__((ext_vector_type(4)));

// ---------------- workspace layout (bytes) ----------------
#define USTATE_OFF  0ull                       // 2*65536*128*4 = 67108864
#define PW_OFF      67108864ull                // packed W1h/W2h (128KB) + W1l/W2l (128KB)
#define STATS_OFF   (PW_OFF + 262144ull)       // float[32]
#define H_OFF       (STATS_OFF + 128ull)       // float[2][256]
#define POOLED0_OFF (H_OFF + 2048ull)          // float[256]
#define PARTS_OFF   (POOLED0_OFF + 1024ull)    // float[3][32][256]
#define WS_END      (PARTS_OFF + 98304ull)
#define ZERO_BYTES  (WS_END - STATS_OFF)

// ---------------- shared memory layout ----------------
#define SM_PW1   0
#define SM_PW2   65536
#define SM_GAMMA 131072
#define SM_BETA  131584
#define SM_B1    132096
#define SM_AH    133120
#define SM_POOL  134144
#define SM_PACC  135168
#define SM_SCR   136192
#define SMEM_BYTES 136320

__device__ __forceinline__ unsigned short f2bf(float f) {
  unsigned u = __builtin_bit_cast(unsigned, f);
  u += 0x7fffu + ((u >> 16) & 1u);     // round-to-nearest-even
  return (unsigned short)(u >> 16);
}
// split a,b into bf16 hi-plane word and bf16 residual(lo)-plane word
__device__ __forceinline__ void split2(float a, float b, unsigned& hw, unsigned& lw) {
  unsigned ha = (unsigned)f2bf(a), hb = (unsigned)f2bf(b);
  float ra = a - __builtin_bit_cast(float, ha << 16);
  float rb = b - __builtin_bit_cast(float, hb << 16);
  hw = ha | (hb << 16);
  lw = (unsigned)f2bf(ra) | ((unsigned)f2bf(rb) << 16);
}
__device__ __forceinline__ float gelu_erf(float x) {
  return 0.5f * x * (1.0f + erff(x * 0.70710678118654752440f));
}
__device__ __forceinline__ floatx4 mfma16(short8 a, short8 b, floatx4 c) {
  return __builtin_amdgcn_mfma_f32_16x16x32_bf16(a, b, c, 0, 0, 0);
}

// ---------------- weight pre-pack: fragment-ready bf16, hi+lo planes ----------------
// pw[0..4095]      = W1 hi frags   (frag f=ct*4+kt: lane l -> row=16ct+(l&15), c=32kt+8(l>>4)+j)
// pw[4096..8191]   = W2 hi frags   (frag f=ct2*8+kt2)
// pw[8192..12287]  = W1 lo frags
// pw[12288..16383] = W2 lo frags
__global__ __launch_bounds__(256) void prep_weights(const float* __restrict__ W1,
                                                    const float* __restrict__ W2,
                                                    int4* __restrict__ pw) {
  int t = blockIdx.x * 256 + threadIdx.x;   // 0..8191
  float v[8];
  if (t < 4096) {
    int f = t >> 6, l = t & 63;
    int ct = f >> 2, kt = f & 3;
    int row = ct * 16 + (l & 15);
    int c = kt * 32 + (l >> 4) * 8;
#pragma unroll
    for (int j = 0; j < 8; ++j) v[j] = W1[(c + j) * 256 + row];
  } else {
    int t2 = t - 4096;
    int f = t2 >> 6, l = t2 & 63;
    int ct2 = f >> 3, kt2 = f & 7;
    int row = ct2 * 16 + (l & 15);
    int c = kt2 * 32 + (l >> 4) * 8;
#pragma unroll
    for (int j = 0; j < 8; ++j) v[j] = W2[(c + j) * 128 + row];
  }
  unsigned hw[4], lw[4];
#pragma unroll
  for (int jj = 0; jj < 4; ++jj) split2(v[2 * jj], v[2 * jj + 1], hw[jj], lw[jj]);
  pw[t]        = make_int4((int)hw[0], (int)hw[1], (int)hw[2], (int)hw[3]);
  pw[8192 + t] = make_int4((int)lw[0], (int)lw[1], (int)lw[2], (int)lw[3]);
}

// ---------------- initial pooled sums + sum|u0| ----------------
__global__ __launch_bounds__(256) void pool0_kernel(const float* __restrict__ u,
                                                    float* __restrict__ pooled0,
                                                    float* __restrict__ stats) {
  int bc = blockIdx.x;  // b*128 + c
  const float4* src = (const float4*)(u + (size_t)bc * NPOS);
  int t = threadIdx.x;
  float s = 0.f, sa = 0.f;
#pragma unroll 4
  for (int i = 0; i < 64; ++i) {
    float4 v = src[i * 256 + t];
    s += v.x + v.y + v.z + v.w;
    sa += fabsf(v.x) + fabsf(v.y) + fabsf(v.z) + fabsf(v.w);
  }
  for (int o = 1; o < 64; o <<= 1) { s += __shfl_xor(s, o, 64); sa += __shfl_xor(sa, o, 64); }
  __shared__ float sc[8];
  int lane = t & 63, w = t >> 6;
  if (lane == 0) { sc[w] = s; sc[4 + w] = sa; }
  __syncthreads();
  if (t == 0) {
    pooled0[bc] = sc[0] + sc[1] + sc[2] + sc[3];
    atomicAdd(&stats[0], sc[4] + sc[5] + sc[6] + sc[7]);
  }
}

// ---------------- fused per-step kernel, 3-product hi/lo MFMA react ----------------
// MODE 0: read d_in u (B,C,THW), write ustate (pos,C)
// MODE 1: in-place ustate
// MODE 2: read ustate, write d_out (B,C,THW)
template <int MODE>
__global__ __launch_bounds__(FTHREADS, 2)
void fused_step(const float* __restrict__ u_in, float* __restrict__ ustate,
                float* __restrict__ d_out, const uint4* __restrict__ pw_g,
                const float* __restrict__ gamma, const float* __restrict__ beta,
                const float* __restrict__ b1, const float* __restrict__ b2,
                const float* __restrict__ Wg, const float* __restrict__ bg,
                const float* __restrict__ Wv, const float* __restrict__ bv,
                const float* __restrict__ alpha_p, const float* __restrict__ logdt_p,
                float* __restrict__ h_g, const float* __restrict__ pooled0,
                float* __restrict__ parts, float* __restrict__ stats, int step) {
  extern __shared__ char smem[];
  uint4* s_pw    = (uint4*)(smem + SM_PW1);
  float* s_gamma = (float*)(smem + SM_GAMMA);
  float* s_beta  = (float*)(smem + SM_BETA);
  float* s_b1    = (float*)(smem + SM_B1);
  float* s_ah    = (float*)(smem + SM_AH);
  float* s_pool  = (float*)(smem + SM_POOL);
  float* s_pacc  = (float*)(smem + SM_PACC);
  float* s_scr   = (float*)(smem + SM_SCR);

  int tid = threadIdx.x;

  // stage hi-plane packed weights into LDS (128 KB = 8192 uint4)
#pragma unroll
  for (int i = 0; i < 16; ++i) s_pw[i * FTHREADS + tid] = pw_g[i * FTHREADS + tid];
  if (tid < 128) { s_gamma[tid] = gamma[tid]; s_beta[tid] = beta[tid]; }
  if (tid >= 128 && tid < 384) s_b1[tid - 128] = b1[tid - 128];
  if (tid < 256) s_pacc[tid] = 0.f;
  // zero the parts slot that step+1 will accumulate into
  {
    int zb = (step + 2) % 3;
#pragma unroll
    for (int i = tid; i < 8192; i += FTHREADS) parts[zb * 8192 + i] = 0.f;
  }
  // pooled means of current state
  if (tid < 256) {
    float ps;
    if (MODE == 0) {
      ps = pooled0[tid];
    } else {
      const float* pp = parts + (size_t)(step % 3) * 8192;
      ps = 0.f;
#pragma unroll
      for (int s = 0; s < 32; ++s) ps += pp[s * 256 + tid];
    }
    s_pool[tid] = ps * (1.0f / 65536.0f);
  }
  __syncthreads();
  // memory pump (redundant per block; block 0 commits h)
  if (tid < 256) {
    int b = tid >> 7, c = tid & 127;
    float gi = bg[c], vi = bv[c];
    const float* pl = s_pool + b * 128;
    for (int k = 0; k < 128; ++k) {
      float pv = pl[k];
      gi = fmaf(pv, Wg[k * 128 + c], gi);
      vi = fmaf(pv, Wv[k * 128 + c], vi);
    }
    float sg = 1.0f / (1.0f + expf(-gi));
    float th = tanhf(vi);
    int hb = step & 1;
    float hn = h_g[hb * 256 + tid] + sg * th;
    if (MODE < 2 && blockIdx.x == 0) h_g[(hb ^ 1) * 256 + tid] = hn;
    float aa = log1pf(expf(alpha_p[0]));  // softplus(alpha)
    s_ah[tid] = aa * hn + b2[c];          // fold b2
  }
  __syncthreads();

  float dtv = fminf(fmaxf(expf(logdt_p[0]), 0.01f), 0.2f);
  int lane = tid & 63, wv = tid >> 6;
  int p = lane & 15, g = lane >> 4;
  int wid = blockIdx.x * 8 + wv;
  float acc_ad = 0.f, acc_au = 0.f;

  for (int it = 0; it < TILES_PER_WAVE; ++it) {
    int tile = wid + it * TOTAL_WAVES;
    int p0 = tile * TILE_P;
    int b = p0 >> 16;
    float preg[8][4];
#pragma unroll
    for (int c8 = 0; c8 < 8; ++c8)
#pragma unroll
      for (int r = 0; r < 4; ++r) preg[c8][r] = 0.f;

#pragma unroll
    for (int pt = 0; pt < 2; ++pt) {
      int pos = p0 + pt * 16 + p;
      int n = pos & (NPOS - 1);

      // ---- X fragments, hi/lo split ----
      short8 bxh[4], bxl[4];
#pragma unroll
      for (int kt = 0; kt < 4; ++kt) {
        float xv[8];
        if (MODE == 0) {
          size_t base = ((size_t)(b * C_DIM + kt * 32 + g * 8)) * NPOS + n;
#pragma unroll
          for (int j = 0; j < 8; ++j) xv[j] = u_in[base + (size_t)j * NPOS];
        } else {
          const float* src = ustate + (size_t)pos * C_DIM + kt * 32 + g * 8;
          float4 qa = *(const float4*)src;
          float4 qb = *(const float4*)(src + 4);
          xv[0] = qa.x; xv[1] = qa.y; xv[2] = qa.z; xv[3] = qa.w;
          xv[4] = qb.x; xv[5] = qb.y; xv[6] = qb.z; xv[7] = qb.w;
        }
        unsigned hw[4], lw[4];
#pragma unroll
        for (int jj = 0; jj < 4; ++jj) split2(xv[2 * jj], xv[2 * jj + 1], hw[jj], lw[jj]);
        bxh[kt] = __builtin_bit_cast(short8, make_int4((int)hw[0], (int)hw[1], (int)hw[2], (int)hw[3]));
        bxl[kt] = __builtin_bit_cast(short8, make_int4((int)lw[0], (int)lw[1], (int)lw[2], (int)lw[3]));
      }

      // ---- GEMM1: 3-product hi/lo (Wh*xh + Wh*xl + Wl*xh) ----
      floatx4 acc1[16];
#pragma unroll
      for (int ct = 0; ct < 16; ++ct) acc1[ct] = (floatx4){0.f, 0.f, 0.f, 0.f};
#pragma unroll
      for (int ct = 0; ct < 16; ++ct) {
#pragma unroll
        for (int kt = 0; kt < 4; ++kt) {
          int f = (ct * 4 + kt) * 64 + lane;
          short8 wh = __builtin_bit_cast(short8, s_pw[f]);
          short8 wl = __builtin_bit_cast(short8, pw_g[8192 + f]);
          acc1[ct] = mfma16(wh, bxh[kt], acc1[ct]);
          acc1[ct] = mfma16(wh, bxl[kt], acc1[ct]);
          acc1[ct] = mfma16(wl, bxh[kt], acc1[ct]);
        }
      }

      // ---- per-kt2: bias+gelu, hi/lo pack, shfl relayout, GEMM2 (3-product) ----
      floatx4 acc2[8];
#pragma unroll
      for (int ct2 = 0; ct2 < 8; ++ct2) acc2[ct2] = (floatx4){0.f, 0.f, 0.f, 0.f};
      int srcA = p + ((g & 1) << 5);
      int srcB = srcA + 16;
      bool hisel = (g >> 1) != 0;
#pragma unroll
      for (int kt2 = 0; kt2 < 8; ++kt2) {
        int pkh[2][2], pkl[2][2];
#pragma unroll
        for (int cc = 0; cc < 2; ++cc) {
          int ct = 2 * kt2 + cc;
          float4 b1v = *(const float4*)(s_b1 + ct * 16 + g * 4);
          float v0 = gelu_erf(acc1[ct][0] + b1v.x);
          float v1 = gelu_erf(acc1[ct][1] + b1v.y);
          float v2 = gelu_erf(acc1[ct][2] + b1v.z);
          float v3 = gelu_erf(acc1[ct][3] + b1v.w);
          unsigned h0, l0, h1, l1;
          split2(v0, v1, h0, l0);
          split2(v2, v3, h1, l1);
          pkh[cc][0] = (int)h0; pkh[cc][1] = (int)h1;
          pkl[cc][0] = (int)l0; pkl[cc][1] = (int)l1;
        }
        // relayout D1 -> B2 fragment (same perm for hi and lo planes)
        int d0a = __shfl(pkh[0][0], srcA, 64), d0b = __shfl(pkh[1][0], srcA, 64);
        int d1a = __shfl(pkh[0][1], srcA, 64), d1b = __shfl(pkh[1][1], srcA, 64);
        int d2a = __shfl(pkh[0][0], srcB, 64), d2b = __shfl(pkh[1][0], srcB, 64);
        int d3a = __shfl(pkh[0][1], srcB, 64), d3b = __shfl(pkh[1][1], srcB, 64);
        int4 qh = make_int4(hisel ? d0b : d0a, hisel ? d1b : d1a,
                            hisel ? d2b : d2a, hisel ? d3b : d3a);
        int e0a = __shfl(pkl[0][0], srcA, 64), e0b = __shfl(pkl[1][0], srcA, 64);
        int e1a = __shfl(pkl[0][1], srcA, 64), e1b = __shfl(pkl[1][1], srcA, 64);
        int e2a = __shfl(pkl[0][0], srcB, 64), e2b = __shfl(pkl[1][0], srcB, 64);
        int e3a = __shfl(pkl[0][1], srcB, 64), e3b = __shfl(pkl[1][1], srcB, 64);
        int4 ql = make_int4(hisel ? e0b : e0a, hisel ? e1b : e1a,
                            hisel ? e2b : e2a, hisel ? e3b : e3a);
        short8 bfh = __builtin_bit_cast(short8, qh);
        short8 bfl = __builtin_bit_cast(short8, ql);
#pragma unroll
        for (int ct2 = 0; ct2 < 8; ++ct2) {
          int f = (ct2 * 8 + kt2) * 64 + lane;
          short8 wh = __builtin_bit_cast(short8, s_pw[4096 + f]);
          short8 wl = __builtin_bit_cast(short8, pw_g[12288 + f]);
          acc2[ct2] = mfma16(wh, bfh, acc2[ct2]);
          acc2[ct2] = mfma16(wh, bfl, acc2[ct2]);
          acc2[ct2] = mfma16(wl, bfh, acc2[ct2]);
        }
      }

      // ---- epilogue: residual + a*h + b2, LayerNorm, stores, reductions ----
      float xr[8][4], ufr[8][4];
      float s1 = 0.f, s2 = 0.f;
#pragma unroll
      for (int ct2 = 0; ct2 < 8; ++ct2) {
        int ch0 = ct2 * 16 + g * 4;
        float uf[4];
        if (MODE == 0) {
          size_t base = ((size_t)(b * C_DIM + ch0)) * NPOS + n;
          uf[0] = u_in[base]; uf[1] = u_in[base + NPOS];
          uf[2] = u_in[base + 2 * (size_t)NPOS]; uf[3] = u_in[base + 3 * (size_t)NPOS];
        } else {
          float4 q = *(const float4*)(ustate + (size_t)pos * C_DIM + ch0);
          uf[0] = q.x; uf[1] = q.y; uf[2] = q.z; uf[3] = q.w;
        }
        float4 ahv = *(const float4*)(s_ah + b * 128 + ch0);
#pragma unroll
        for (int r = 0; r < 4; ++r) {
          float ah = (r == 0) ? ahv.x : (r == 1) ? ahv.y : (r == 2) ? ahv.z : ahv.w;
          float du = acc2[ct2][r] + ah;
          float x = uf[r] + dtv * du;
          xr[ct2][r] = x; ufr[ct2][r] = uf[r];
          s1 += x; s2 += x * x;
        }
      }
      s1 += __shfl_xor(s1, 16, 64); s1 += __shfl_xor(s1, 32, 64);
      s2 += __shfl_xor(s2, 16, 64); s2 += __shfl_xor(s2, 32, 64);
      float mean = s1 * (1.0f / 128.0f);
      float var = s2 * (1.0f / 128.0f) - mean * mean;
      float rstd = rsqrtf(var + 1e-5f);
#pragma unroll
      for (int ct2 = 0; ct2 < 8; ++ct2) {
        int ch0 = ct2 * 16 + g * 4;
        float4 gm = *(const float4*)(s_gamma + ch0);
        float4 bt = *(const float4*)(s_beta + ch0);
        float un[4];
        un[0] = (xr[ct2][0] - mean) * rstd * gm.x + bt.x;
        un[1] = (xr[ct2][1] - mean) * rstd * gm.y + bt.y;
        un[2] = (xr[ct2][2] - mean) * rstd * gm.z + bt.z;
        un[3] = (xr[ct2][3] - mean) * rstd * gm.w + bt.w;
        if (MODE == 2) {
          size_t base = ((size_t)(b * C_DIM + ch0)) * NPOS + n;
          d_out[base] = un[0]; d_out[base + NPOS] = un[1];
          d_out[base + 2 * (size_t)NPOS] = un[2]; d_out[base + 3 * (size_t)NPOS] = un[3];
        } else {
          *(float4*)(ustate + (size_t)pos * C_DIM + ch0) =
              make_float4(un[0], un[1], un[2], un[3]);
        }
#pragma unroll
        for (int r = 0; r < 4; ++r) {
          acc_ad += fabsf(un[r] - ufr[ct2][r]);
          acc_au += fabsf(un[r]);
          if (MODE < 2) preg[ct2][r] += un[r];
        }
      }
    }  // pt loop

    // per-tile pooled flush into LDS accumulator (this tile's batch)
    if (MODE < 2) {
#pragma unroll
      for (int ct2 = 0; ct2 < 8; ++ct2) {
#pragma unroll
        for (int r = 0; r < 4; ++r) {
          float v = preg[ct2][r];
          v += __shfl_xor(v, 1, 64); v += __shfl_xor(v, 2, 64);
          v += __shfl_xor(v, 4, 64); v += __shfl_xor(v, 8, 64);
          if (p == 0) unsafeAtomicAdd(&s_pacc[b * 128 + ct2 * 16 + g * 4 + r], v);
        }
      }
    }
  }  // tile loop

  // scalar reductions
  for (int o = 1; o < 64; o <<= 1) {
    acc_ad += __shfl_xor(acc_ad, o, 64);
    acc_au += __shfl_xor(acc_au, o, 64);
  }
  if (lane == 0) { s_scr[wv * 2] = acc_ad; s_scr[wv * 2 + 1] = acc_au; }
  __syncthreads();
  if (tid == 0) {
    float ad = 0.f, au = 0.f;
#pragma unroll
    for (int w = 0; w < 8; ++w) { ad += s_scr[w * 2]; au += s_scr[w * 2 + 1]; }
    atomicAdd(&stats[17 + step], ad);  // sum|u_new - u_prev|
    atomicAdd(&stats[step + 1], au);   // sum|u_new|
  }
  __syncthreads();
  if (MODE < 2 && tid < 256) {
    atomicAdd(&parts[(size_t)((step + 1) % 3) * 8192 + (blockIdx.x & 31) * 256 + tid],
              s_pacc[tid]);
  }
}

__global__ void finalize_kernel(const float* __restrict__ stats, float* __restrict__ out) {
  if (threadIdx.x == 0 && blockIdx.x == 0) {
    const float inv = 1.0f / 16777216.0f;  // mean over B*N*C
    float tm = 0.f;
#pragma unroll
    for (int k = 1; k <= 12; ++k)
      tm += (stats[16 + k] * inv) / (stats[k - 1] * inv + 1e-8f);
    out[16777216] = tm * (1.0f / 12.0f);
  }
}

extern "C" void kernel_launch(void* const* d_in, const int* in_sizes, int n_in,
                              void* d_out, int out_size, void* d_ws, size_t ws_size,
                              hipStream_t stream) {
  const float* u     = (const float*)d_in[0];
  const float* Wg    = (const float*)d_in[1];
  const float* bg    = (const float*)d_in[2];
  const float* Wv    = (const float*)d_in[3];
  const float* bv    = (const float*)d_in[4];
  const float* W1    = (const float*)d_in[5];
  const float* b1    = (const float*)d_in[6];
  const float* W2    = (const float*)d_in[7];
  const float* b2    = (const float*)d_in[8];
  const float* gamma = (const float*)d_in[9];
  const float* beta  = (const float*)d_in[10];
  const float* alpha = (const float*)d_in[11];
  const float* logdt = (const float*)d_in[12];
  float* out = (float*)d_out;
  char* ws = (char*)d_ws;
  if (ws_size < WS_END) return;

  float* ustate  = (float*)(ws + USTATE_OFF);
  int4*  pw      = (int4*)(ws + PW_OFF);
  float* stats   = (float*)(ws + STATS_OFF);
  float* h_g     = (float*)(ws + H_OFF);
  float* pooled0 = (float*)(ws + POOLED0_OFF);
  float* parts   = (float*)(ws + PARTS_OFF);

  hipFuncSetAttribute(reinterpret_cast<const void*>(&fused_step<0>),
                      hipFuncAttributeMaxDynamicSharedMemorySize, SMEM_BYTES);
  hipFuncSetAttribute(reinterpret_cast<const void*>(&fused_step<1>),
                      hipFuncAttributeMaxDynamicSharedMemorySize, SMEM_BYTES);
  hipFuncSetAttribute(reinterpret_cast<const void*>(&fused_step<2>),
                      hipFuncAttributeMaxDynamicSharedMemorySize, SMEM_BYTES);

  hipMemsetAsync(ws + STATS_OFF, 0, ZERO_BYTES, stream);
  prep_weights<<<32, 256, 0, stream>>>(W1, W2, pw);
  pool0_kernel<<<256, 256, 0, stream>>>(u, pooled0, stats);

  for (int step = 0; step < NSTEPS; ++step) {
    if (step == 0)
      fused_step<0><<<FBLOCKS, FTHREADS, SMEM_BYTES, stream>>>(
          u, ustate, out, (const uint4*)pw, gamma, beta, b1, b2, Wg, bg, Wv, bv,
          alpha, logdt, h_g, pooled0, parts, stats, step);
    else if (step == NSTEPS - 1)
      fused_step<2><<<FBLOCKS, FTHREADS, SMEM_BYTES, stream>>>(
          u, ustate, out, (const uint4*)pw, gamma, beta, b1, b2, Wg, bg, Wv, bv,
          alpha, logdt, h_g, pooled0, parts, stats, step);
    else
      fused_step<1><<<FBLOCKS, FTHREADS, SMEM_BYTES, stream>>>(
          u, ustate, out, (const uint4*)pw, gamma, beta, b1, b2, Wg, bg, Wv, bv,
          alpha, logdt, h_g, pooled0, parts, stats, step);
  }
  finalize_kernel<<<1, 64, 0, stream>>>(stats, out);
}

// Round 7
// 3586.523 us; speedup vs baseline: 1.7649x; 1.7649x over previous
//
#include <hip/hip_runtime.h>

#define C_DIM 128
#define NPOS 65536
#define NSTEPS 12
#define FBLOCKS 256
#define FTHREADS 512
#define TOTAL_WAVES 2048
#define TILES_PER_WAVE 2

typedef short short8 __attribute__((ext_vector_type(8)));
typedef float floatx4 __attribute__((ext_vector_type(4)));

// ---------------- workspace layout (bytes) ----------------
// ustate: channel-major (b, c, n) -- SAME layout as input u / output
#define USTATE_OFF  0ull                       // 2*128*65536*4 = 67108864
#define Y1_OFF      67108864ull                // [4096 tiles][256 ch][32 pos] fp32 = 134217728
#define PW_OFF      201326592ull               // packed W1h/W2h + W1l/W2l = 256KB
#define STATS_OFF   (PW_OFF + 262144ull)       // float[32]
#define H_OFF       (STATS_OFF + 128ull)       // float[2][256]
#define POOLED0_OFF (H_OFF + 2048ull)          // float[256]
#define PARTS_OFF   (POOLED0_OFF + 1024ull)    // float[3][32][256]
#define WS_END      (PARTS_OFF + 98304ull)
#define ZERO_BYTES  (WS_END - STATS_OFF)

// ---------------- kernel A shared memory (GEMM1) ----------------
#define SMA_W1H 0
#define SMA_W1L 65536
#define SMA_B1  131072
#define SMEM_A  132096

// ---------------- kernel B shared memory (GEMM2 + epilogue) ----------------
#define SMB_W2H   0
#define SMB_W2L   65536
#define SMB_GAMMA 131072
#define SMB_BETA  131584
#define SMB_AH    132096
#define SMB_POOL  133120
#define SMB_PACC  134144
#define SMB_SCR   135168
#define SMEM_B    135232

__device__ __forceinline__ unsigned short f2bf(float f) {
  unsigned u = __builtin_bit_cast(unsigned, f);
  u += 0x7fffu + ((u >> 16) & 1u);     // round-to-nearest-even
  return (unsigned short)(u >> 16);
}
// split a,b into bf16 hi-plane word and bf16 residual(lo)-plane word
__device__ __forceinline__ void split2(float a, float b, unsigned& hw, unsigned& lw) {
  unsigned ha = (unsigned)f2bf(a), hb = (unsigned)f2bf(b);
  float ra = a - __builtin_bit_cast(float, ha << 16);
  float rb = b - __builtin_bit_cast(float, hb << 16);
  hw = ha | (hb << 16);
  lw = (unsigned)f2bf(ra) | ((unsigned)f2bf(rb) << 16);
}
__device__ __forceinline__ float gelu_erf(float x) {
  return 0.5f * x * (1.0f + erff(x * 0.70710678118654752440f));
}
__device__ __forceinline__ floatx4 mfma16(short8 a, short8 b, floatx4 c) {
  return __builtin_amdgcn_mfma_f32_16x16x32_bf16(a, b, c, 0, 0, 0);
}

// ---------------- weight pre-pack: fragment-ready bf16, hi+lo planes ----------------
// pw[0..4095]      = W1 hi frags (f=ct*4+kt: lane l -> row=16ct+(l&15), c=32kt+8(l>>4)+j)
// pw[4096..8191]   = W2 hi frags (f=ct2*8+kt2)
// pw[8192..12287]  = W1 lo frags
// pw[12288..16383] = W2 lo frags
__global__ __launch_bounds__(256) void prep_weights(const float* __restrict__ W1,
                                                    const float* __restrict__ W2,
                                                    int4* __restrict__ pw) {
  int t = blockIdx.x * 256 + threadIdx.x;   // 0..8191
  float v[8];
  if (t < 4096) {
    int f = t >> 6, l = t & 63;
    int ct = f >> 2, kt = f & 3;
    int row = ct * 16 + (l & 15);
    int c = kt * 32 + (l >> 4) * 8;
#pragma unroll
    for (int j = 0; j < 8; ++j) v[j] = W1[(c + j) * 256 + row];
  } else {
    int t2 = t - 4096;
    int f = t2 >> 6, l = t2 & 63;
    int ct2 = f >> 3, kt2 = f & 7;
    int row = ct2 * 16 + (l & 15);
    int c = kt2 * 32 + (l >> 4) * 8;
#pragma unroll
    for (int j = 0; j < 8; ++j) v[j] = W2[(c + j) * 128 + row];
  }
  unsigned hw[4], lw[4];
#pragma unroll
  for (int jj = 0; jj < 4; ++jj) split2(v[2 * jj], v[2 * jj + 1], hw[jj], lw[jj]);
  pw[t]        = make_int4((int)hw[0], (int)hw[1], (int)hw[2], (int)hw[3]);
  pw[8192 + t] = make_int4((int)lw[0], (int)lw[1], (int)lw[2], (int)lw[3]);
}

// ---------------- initial pooled sums + sum|u0| ----------------
__global__ __launch_bounds__(256) void pool0_kernel(const float* __restrict__ u,
                                                    float* __restrict__ pooled0,
                                                    float* __restrict__ stats) {
  int bc = blockIdx.x;  // b*128 + c
  const float4* src = (const float4*)(u + (size_t)bc * NPOS);
  int t = threadIdx.x;
  float s = 0.f, sa = 0.f;
#pragma unroll 4
  for (int i = 0; i < 64; ++i) {
    float4 v = src[i * 256 + t];
    s += v.x + v.y + v.z + v.w;
    sa += fabsf(v.x) + fabsf(v.y) + fabsf(v.z) + fabsf(v.w);
  }
  for (int o = 1; o < 64; o <<= 1) { s += __shfl_xor(s, o, 64); sa += __shfl_xor(sa, o, 64); }
  __shared__ float sc[8];
  int lane = t & 63, w = t >> 6;
  if (lane == 0) { sc[w] = s; sc[4 + w] = sa; }
  __syncthreads();
  if (t == 0) {
    pooled0[bc] = sc[0] + sc[1] + sc[2] + sc[3];
    atomicAdd(&stats[0], sc[4] + sc[5] + sc[6] + sc[7]);
  }
}

// ---------------- kernel A: y1 = gelu(x @ W1 + b1), 3-product hi/lo, W1 planes in LDS ----
// src is channel-major (b, c, n) — either d_in u (step 0) or ustate.
// y1 layout: [tile][ch 256][pos 32]
__global__ __launch_bounds__(FTHREADS)
void react1_kernel(const float* __restrict__ src, float* __restrict__ y1,
                   const uint4* __restrict__ pw_g, const float* __restrict__ b1) {
  extern __shared__ char smem[];
  uint4* s_w1h = (uint4*)(smem + SMA_W1H);
  uint4* s_w1l = (uint4*)(smem + SMA_W1L);
  float* s_b1  = (float*)(smem + SMA_B1);

  int tid = threadIdx.x;
#pragma unroll
  for (int i = 0; i < 8; ++i) {
    s_w1h[i * FTHREADS + tid] = pw_g[i * FTHREADS + tid];
    s_w1l[i * FTHREADS + tid] = pw_g[8192 + i * FTHREADS + tid];
  }
  if (tid < 256) s_b1[tid] = b1[tid];
  __syncthreads();

  int lane = tid & 63, wv = tid >> 6;
  int p = lane & 15, g = lane >> 4;
  int wid = blockIdx.x * 8 + wv;

  for (int it = 0; it < TILES_PER_WAVE; ++it) {
    int tile = wid + it * TOTAL_WAVES;
    int p0 = tile * 32;
    int b = tile >> 11;                // 2048 tiles per batch
    int n0 = p0 & (NPOS - 1);
#pragma unroll
    for (int pt = 0; pt < 2; ++pt) {
      int n = n0 + pt * 16 + p;

      // ---- X fragments from channel-major src (dense 64B granules across p) ----
      short8 bxh[4], bxl[4];
#pragma unroll
      for (int kt = 0; kt < 4; ++kt) {
        float xv[8];
        size_t base = ((size_t)(b * C_DIM + kt * 32 + g * 8)) * NPOS + n;
#pragma unroll
        for (int j = 0; j < 8; ++j) xv[j] = src[base + (size_t)j * NPOS];
        unsigned hw[4], lw[4];
#pragma unroll
        for (int jj = 0; jj < 4; ++jj) split2(xv[2 * jj], xv[2 * jj + 1], hw[jj], lw[jj]);
        bxh[kt] = __builtin_bit_cast(short8, make_int4((int)hw[0], (int)hw[1], (int)hw[2], (int)hw[3]));
        bxl[kt] = __builtin_bit_cast(short8, make_int4((int)lw[0], (int)lw[1], (int)lw[2], (int)lw[3]));
      }

      // ---- GEMM1: Wh*xh + Wh*xl + Wl*xh (same accumulation order as round 5) ----
      floatx4 acc1[16];
#pragma unroll
      for (int ct = 0; ct < 16; ++ct) acc1[ct] = (floatx4){0.f, 0.f, 0.f, 0.f};
#pragma unroll
      for (int ct = 0; ct < 16; ++ct) {
#pragma unroll
        for (int kt = 0; kt < 4; ++kt) {
          int f = (ct * 4 + kt) * 64 + lane;
          short8 wh = __builtin_bit_cast(short8, s_w1h[f]);
          short8 wl = __builtin_bit_cast(short8, s_w1l[f]);
          acc1[ct] = mfma16(wh, bxh[kt], acc1[ct]);
          acc1[ct] = mfma16(wh, bxl[kt], acc1[ct]);
          acc1[ct] = mfma16(wl, bxh[kt], acc1[ct]);
        }
      }

      // ---- bias + gelu -> y1[tile][ch][pos]: dense across the 16 p-lanes ----
      float* dst = y1 + (size_t)tile * 8192 + pt * 16 + p;
#pragma unroll
      for (int ct = 0; ct < 16; ++ct) {
        int ch0 = ct * 16 + g * 4;
        float4 b1v = *(const float4*)(s_b1 + ch0);
        dst[(ch0 + 0) * 32] = gelu_erf(acc1[ct][0] + b1v.x);
        dst[(ch0 + 1) * 32] = gelu_erf(acc1[ct][1] + b1v.y);
        dst[(ch0 + 2) * 32] = gelu_erf(acc1[ct][2] + b1v.z);
        dst[(ch0 + 3) * 32] = gelu_erf(acc1[ct][3] + b1v.w);
      }
    }
  }
}

// ---------------- kernel B: react = y1 @ W2; pump; LN; stats; W2 planes in LDS --------
// MODE 0: first step (pooled from pooled0), src=u, dst=ustate
// MODE 1: middle step (pooled from parts), src=ustate, dst=ustate
// MODE 2: last step (pooled from parts, no h/parts update), src=ustate, dst=d_out
// src and dst are channel-major (b, c, n).
template <int MODE>
__global__ __launch_bounds__(FTHREADS)
void react2_kernel(const float* __restrict__ src, float* __restrict__ dst,
                   const float* __restrict__ y1, const uint4* __restrict__ pw_g,
                   const float* __restrict__ gamma, const float* __restrict__ beta,
                   const float* __restrict__ b2,
                   const float* __restrict__ Wg, const float* __restrict__ bg,
                   const float* __restrict__ Wv, const float* __restrict__ bv,
                   const float* __restrict__ alpha_p, const float* __restrict__ logdt_p,
                   float* __restrict__ h_g, const float* __restrict__ pooled0,
                   float* __restrict__ parts, float* __restrict__ stats, int step) {
  extern __shared__ char smem[];
  uint4* s_w2h   = (uint4*)(smem + SMB_W2H);
  uint4* s_w2l   = (uint4*)(smem + SMB_W2L);
  float* s_gamma = (float*)(smem + SMB_GAMMA);
  float* s_beta  = (float*)(smem + SMB_BETA);
  float* s_ah    = (float*)(smem + SMB_AH);
  float* s_pool  = (float*)(smem + SMB_POOL);
  float* s_pacc  = (float*)(smem + SMB_PACC);
  float* s_scr   = (float*)(smem + SMB_SCR);

  int tid = threadIdx.x;
#pragma unroll
  for (int i = 0; i < 8; ++i) {
    s_w2h[i * FTHREADS + tid] = pw_g[4096 + i * FTHREADS + tid];
    s_w2l[i * FTHREADS + tid] = pw_g[12288 + i * FTHREADS + tid];
  }
  if (tid < 128) { s_gamma[tid] = gamma[tid]; s_beta[tid] = beta[tid]; }
  if (tid < 256) s_pacc[tid] = 0.f;
  // zero the parts slot that step+1 will accumulate into
  {
    int zb = (step + 2) % 3;
#pragma unroll
    for (int i = tid; i < 8192; i += FTHREADS) parts[zb * 8192 + i] = 0.f;
  }
  // pooled means of current state
  if (tid < 256) {
    float ps;
    if (MODE == 0) {
      ps = pooled0[tid];
    } else {
      const float* pp = parts + (size_t)(step % 3) * 8192;
      ps = 0.f;
#pragma unroll
      for (int s = 0; s < 32; ++s) ps += pp[s * 256 + tid];
    }
    s_pool[tid] = ps * (1.0f / 65536.0f);
  }
  __syncthreads();
  // memory pump (redundant per block; block 0 commits h)
  if (tid < 256) {
    int b = tid >> 7, c = tid & 127;
    float gi = bg[c], vi = bv[c];
    const float* pl = s_pool + b * 128;
    for (int k = 0; k < 128; ++k) {
      float pv = pl[k];
      gi = fmaf(pv, Wg[k * 128 + c], gi);
      vi = fmaf(pv, Wv[k * 128 + c], vi);
    }
    float sg = 1.0f / (1.0f + expf(-gi));
    float th = tanhf(vi);
    int hb = step & 1;
    float hn = h_g[hb * 256 + tid] + sg * th;
    if (MODE < 2 && blockIdx.x == 0) h_g[(hb ^ 1) * 256 + tid] = hn;
    float aa = log1pf(expf(alpha_p[0]));  // softplus(alpha)
    s_ah[tid] = aa * hn + b2[c];          // fold b2
  }
  __syncthreads();

  float dtv = fminf(fmaxf(expf(logdt_p[0]), 0.01f), 0.2f);
  int lane = tid & 63, wv = tid >> 6;
  int p = lane & 15, g = lane >> 4;
  int wid = blockIdx.x * 8 + wv;
  float acc_ad = 0.f, acc_au = 0.f;

  for (int it = 0; it < TILES_PER_WAVE; ++it) {
    int tile = wid + it * TOTAL_WAVES;
    int p0 = tile * 32;
    int b = tile >> 11;
    int n0 = p0 & (NPOS - 1);
    float preg[8][4];
#pragma unroll
    for (int c8 = 0; c8 < 8; ++c8)
#pragma unroll
      for (int r = 0; r < 4; ++r) preg[c8][r] = 0.f;

#pragma unroll
    for (int pt = 0; pt < 2; ++pt) {
      int n = n0 + pt * 16 + p;

      // ---- y1 fragments from [tile][ch][pos] (dense across p), hi/lo split ----
      const float* ysrc = y1 + (size_t)tile * 8192 + pt * 16 + p;
      short8 byh[8], byl[8];
#pragma unroll
      for (int kt2 = 0; kt2 < 8; ++kt2) {
        int chb = kt2 * 32 + g * 8;
        float yv[8];
#pragma unroll
        for (int j = 0; j < 8; ++j) yv[j] = ysrc[(chb + j) * 32];
        unsigned hw[4], lw[4];
#pragma unroll
        for (int jj = 0; jj < 4; ++jj) split2(yv[2 * jj], yv[2 * jj + 1], hw[jj], lw[jj]);
        byh[kt2] = __builtin_bit_cast(short8, make_int4((int)hw[0], (int)hw[1], (int)hw[2], (int)hw[3]));
        byl[kt2] = __builtin_bit_cast(short8, make_int4((int)lw[0], (int)lw[1], (int)lw[2], (int)lw[3]));
      }

      // ---- GEMM2: Wh*yh + Wh*yl + Wl*yh (same accumulation order as round 5) ----
      floatx4 acc2[8];
#pragma unroll
      for (int ct2 = 0; ct2 < 8; ++ct2) acc2[ct2] = (floatx4){0.f, 0.f, 0.f, 0.f};
#pragma unroll
      for (int ct2 = 0; ct2 < 8; ++ct2) {
#pragma unroll
        for (int kt2 = 0; kt2 < 8; ++kt2) {
          int f = (ct2 * 8 + kt2) * 64 + lane;
          short8 wh = __builtin_bit_cast(short8, s_w2h[f]);
          short8 wl = __builtin_bit_cast(short8, s_w2l[f]);
          acc2[ct2] = mfma16(wh, byh[kt2], acc2[ct2]);
          acc2[ct2] = mfma16(wh, byl[kt2], acc2[ct2]);
          acc2[ct2] = mfma16(wl, byh[kt2], acc2[ct2]);
        }
      }

      // ---- epilogue: residual + a*h + b2, LayerNorm, stores, reductions ----
      float xr[8][4], ufr[8][4];
      float s1 = 0.f, s2 = 0.f;
#pragma unroll
      for (int ct2 = 0; ct2 < 8; ++ct2) {
        int ch0 = ct2 * 16 + g * 4;
        size_t base = ((size_t)(b * C_DIM + ch0)) * NPOS + n;
        float uf[4];
        uf[0] = src[base];
        uf[1] = src[base + NPOS];
        uf[2] = src[base + 2 * (size_t)NPOS];
        uf[3] = src[base + 3 * (size_t)NPOS];
        float4 ahv = *(const float4*)(s_ah + b * 128 + ch0);
#pragma unroll
        for (int r = 0; r < 4; ++r) {
          float ah = (r == 0) ? ahv.x : (r == 1) ? ahv.y : (r == 2) ? ahv.z : ahv.w;
          float du = acc2[ct2][r] + ah;
          float x = uf[r] + dtv * du;
          xr[ct2][r] = x; ufr[ct2][r] = uf[r];
          s1 += x; s2 += x * x;
        }
      }
      s1 += __shfl_xor(s1, 16, 64); s1 += __shfl_xor(s1, 32, 64);
      s2 += __shfl_xor(s2, 16, 64); s2 += __shfl_xor(s2, 32, 64);
      float mean = s1 * (1.0f / 128.0f);
      float var = s2 * (1.0f / 128.0f) - mean * mean;
      float rstd = rsqrtf(var + 1e-5f);
#pragma unroll
      for (int ct2 = 0; ct2 < 8; ++ct2) {
        int ch0 = ct2 * 16 + g * 4;
        size_t base = ((size_t)(b * C_DIM + ch0)) * NPOS + n;
        float4 gm = *(const float4*)(s_gamma + ch0);
        float4 bt = *(const float4*)(s_beta + ch0);
        float un[4];
        un[0] = (xr[ct2][0] - mean) * rstd * gm.x + bt.x;
        un[1] = (xr[ct2][1] - mean) * rstd * gm.y + bt.y;
        un[2] = (xr[ct2][2] - mean) * rstd * gm.z + bt.z;
        un[3] = (xr[ct2][3] - mean) * rstd * gm.w + bt.w;
        dst[base]                    = un[0];
        dst[base + NPOS]             = un[1];
        dst[base + 2 * (size_t)NPOS] = un[2];
        dst[base + 3 * (size_t)NPOS] = un[3];
#pragma unroll
        for (int r = 0; r < 4; ++r) {
          acc_ad += fabsf(un[r] - ufr[ct2][r]);
          acc_au += fabsf(un[r]);
          if (MODE < 2) preg[ct2][r] += un[r];
        }
      }
    }  // pt loop

    // per-tile pooled flush into LDS accumulator
    if (MODE < 2) {
#pragma unroll
      for (int ct2 = 0; ct2 < 8; ++ct2) {
#pragma unroll
        for (int r = 0; r < 4; ++r) {
          float v = preg[ct2][r];
          v += __shfl_xor(v, 1, 64); v += __shfl_xor(v, 2, 64);
          v += __shfl_xor(v, 4, 64); v += __shfl_xor(v, 8, 64);
          if (p == 0) unsafeAtomicAdd(&s_pacc[b * 128 + ct2 * 16 + g * 4 + r], v);
        }
      }
    }
  }  // tile loop

  // scalar reductions
  for (int o = 1; o < 64; o <<= 1) {
    acc_ad += __shfl_xor(acc_ad, o, 64);
    acc_au += __shfl_xor(acc_au, o, 64);
  }
  if (lane == 0) { s_scr[wv * 2] = acc_ad; s_scr[wv * 2 + 1] = acc_au; }
  __syncthreads();
  if (tid == 0) {
    float ad = 0.f, au = 0.f;
#pragma unroll
    for (int w = 0; w < 8; ++w) { ad += s_scr[w * 2]; au += s_scr[w * 2 + 1]; }
    atomicAdd(&stats[17 + step], ad);  // sum|u_new - u_prev|
    atomicAdd(&stats[step + 1], au);   // sum|u_new|
  }
  __syncthreads();
  if (MODE < 2 && tid < 256) {
    atomicAdd(&parts[(size_t)((step + 1) % 3) * 8192 + (blockIdx.x & 31) * 256 + tid],
              s_pacc[tid]);
  }
}

__global__ void finalize_kernel(const float* __restrict__ stats, float* __restrict__ out) {
  if (threadIdx.x == 0 && blockIdx.x == 0) {
    const float inv = 1.0f / 16777216.0f;  // mean over B*N*C
    float tm = 0.f;
#pragma unroll
    for (int k = 1; k <= 12; ++k)
      tm += (stats[16 + k] * inv) / (stats[k - 1] * inv + 1e-8f);
    out[16777216] = tm * (1.0f / 12.0f);
  }
}

extern "C" void kernel_launch(void* const* d_in, const int* in_sizes, int n_in,
                              void* d_out, int out_size, void* d_ws, size_t ws_size,
                              hipStream_t stream) {
  const float* u     = (const float*)d_in[0];
  const float* Wg    = (const float*)d_in[1];
  const float* bg    = (const float*)d_in[2];
  const float* Wv    = (const float*)d_in[3];
  const float* bv    = (const float*)d_in[4];
  const float* W1    = (const float*)d_in[5];
  const float* b1    = (const float*)d_in[6];
  const float* W2    = (const float*)d_in[7];
  const float* b2    = (const float*)d_in[8];
  const float* gamma = (const float*)d_in[9];
  const float* beta  = (const float*)d_in[10];
  const float* alpha = (const float*)d_in[11];
  const float* logdt = (const float*)d_in[12];
  float* out = (float*)d_out;
  char* ws = (char*)d_ws;
  if (ws_size < WS_END) return;

  float* ustate  = (float*)(ws + USTATE_OFF);
  float* y1      = (float*)(ws + Y1_OFF);
  int4*  pw      = (int4*)(ws + PW_OFF);
  float* stats   = (float*)(ws + STATS_OFF);
  float* h_g     = (float*)(ws + H_OFF);
  float* pooled0 = (float*)(ws + POOLED0_OFF);
  float* parts   = (float*)(ws + PARTS_OFF);

  hipFuncSetAttribute(reinterpret_cast<const void*>(&react1_kernel),
                      hipFuncAttributeMaxDynamicSharedMemorySize, SMEM_A);
  hipFuncSetAttribute(reinterpret_cast<const void*>(&react2_kernel<0>),
                      hipFuncAttributeMaxDynamicSharedMemorySize, SMEM_B);
  hipFuncSetAttribute(reinterpret_cast<const void*>(&react2_kernel<1>),
                      hipFuncAttributeMaxDynamicSharedMemorySize, SMEM_B);
  hipFuncSetAttribute(reinterpret_cast<const void*>(&react2_kernel<2>),
                      hipFuncAttributeMaxDynamicSharedMemorySize, SMEM_B);

  hipMemsetAsync(ws + STATS_OFF, 0, ZERO_BYTES, stream);
  prep_weights<<<32, 256, 0, stream>>>(W1, W2, pw);
  pool0_kernel<<<256, 256, 0, stream>>>(u, pooled0, stats);

  for (int step = 0; step < NSTEPS; ++step) {
    const float* src = (step == 0) ? u : (const float*)ustate;
    react1_kernel<<<FBLOCKS, FTHREADS, SMEM_A, stream>>>(src, y1, (const uint4*)pw, b1);

    if (step == 0)
      react2_kernel<0><<<FBLOCKS, FTHREADS, SMEM_B, stream>>>(
          u, ustate, y1, (const uint4*)pw, gamma, beta, b2, Wg, bg, Wv, bv,
          alpha, logdt, h_g, pooled0, parts, stats, step);
    else if (step == NSTEPS - 1)
      react2_kernel<2><<<FBLOCKS, FTHREADS, SMEM_B, stream>>>(
          ustate, out, y1, (const uint4*)pw, gamma, beta, b2, Wg, bg, Wv, bv,
          alpha, logdt, h_g, pooled0, parts, stats, step);
    else
      react2_kernel<1><<<FBLOCKS, FTHREADS, SMEM_B, stream>>>(
          ustate, ustate, y1, (const uint4*)pw, gamma, beta, b2, Wg, bg, Wv, bv,
          alpha, logdt, h_g, pooled0, parts, stats, step);
  }
  finalize_kernel<<<1, 64, 0, stream>>>(stats, out);
}